// Round 4
// baseline (859.610 us; speedup 1.0000x reference)
//
#include <hip/hip_runtime.h>
#include <math.h>

// MultiHash: Instant-NGP style 2D multires hash encoding (L=16, T=2^14, F=2)
// + MLP 32 -> 64 -> 64 -> 3, fp32 throughout (threshold 8.9e-8 abs forbids bf16).
//
// R4: cooperative 4-wave split. R1-R3 post-mortem: any structure with a
// 64-float per-thread array gets stashed in AGPRs/scratch (VGPR_Count 48-60)
// and every access pays v_accvgpr_read/write VALU ops -> ~19k VALU inst/wave
// vs ~7k ideal. Restructure so no thread holds >16 accumulators:
//   block = 256 thr = 4 waves, 64 samples. lane = sample, wave q = neuron
//   quarter. Wave q computes levels 4q..4q+3 (encoding), h1[16q..16q+16),
//   h2[16q..16q+16) + layer-3 partials. feat[32]/h1[64] exchanged via LDS
//   (+1-padded strides: 33/65 floats -> 2-way bank aliasing, free per m136;
//   all LDS offsets are immediates). Neuron index j=16q+jj is wave-uniform ->
//   W1/W2/W3 loads stay scalar (s_load), VALU stays pure FMA.

#define TBL_MASK 16383u
#define PRIME1   2654435761u
#define FSTRIDE  33   // feat row stride (floats): 33 mod 32 = 1 -> 2-way only
#define HSTRIDE  65   // h1 row stride: 65 mod 32 = 1 -> 2-way only
#define OSTRIDE  13   // o_part row stride (12 used): 13 coprime 32 -> 2-way

struct ResArr { float r[16]; };

__global__ __launch_bounds__(256) void mh_fused(
    const float* __restrict__ x,
    const float* __restrict__ tables,
    const float* __restrict__ W1,
    const float* __restrict__ b1,
    const float* __restrict__ W2,
    const float* __restrict__ b2,
    const float* __restrict__ W3,
    const float* __restrict__ b3,
    float* __restrict__ out,
    ResArr res, int n)
{
    __shared__ float h1_s[64 * HSTRIDE];           // 16640 B
    __shared__ float fo_s[64 * FSTRIDE];           // 8448 B; feat, then o_part

    const int tid  = threadIdx.x;
    const int lane = tid & 63;          // sample within block
    const int q    = tid >> 6;          // wave id: neuron/level quarter
    const long s   = (long)blockIdx.x * 64 + lane; // global sample
    const bool live = (s < (long)n);

    float2 xv = make_float2(0.0f, 0.0f);
    if (live) xv = reinterpret_cast<const float2*>(x)[s];

    const float2* __restrict__ tbl2 = reinterpret_cast<const float2*>(tables);

    // ---- Phase E: encoding, levels lv = 4q + e ------------------------------
    {
        float* fptr = fo_s + lane * FSTRIDE + q * 8;
        #pragma unroll
        for (int e = 0; e < 4; ++e) {
            const int lv   = q * 4 + e;
            const float r  = res.r[lv];
            const float sx = xv.x * r;
            const float sy = xv.y * r;
            const float gx = floorf(sx);
            const float gy = floorf(sy);
            const unsigned ux = (unsigned)(int)gx;
            const unsigned uy = (unsigned)(int)gy;
            const unsigned hy0 = uy * PRIME1;
            const unsigned hy1 = hy0 + PRIME1;          // (uy+1)*PRIME1 mod 2^32
            const unsigned i00 = ( ux       ^ hy0) & TBL_MASK;
            const unsigned i10 = ((ux + 1u) ^ hy0) & TBL_MASK;
            const unsigned i01 = ( ux       ^ hy1) & TBL_MASK;
            const unsigned i11 = ((ux + 1u) ^ hy1) & TBL_MASK;
            const float2* tl = tbl2 + (lv << 14);
            const float2 t00 = tl[i00];
            const float2 t10 = tl[i10];
            const float2 t01 = tl[i01];
            const float2 t11 = tl[i11];
            const float wx0 = 1.0f - fabsf(sx - gx);
            const float wx1 = 1.0f - fabsf(sx - (gx + 1.0f));
            const float wy0 = 1.0f - fabsf(sy - gy);
            const float wy1 = 1.0f - fabsf(sy - (gy + 1.0f));
            const float w00 = wx0 * wy0;
            const float w10 = wx1 * wy0;
            const float w01 = wx0 * wy1;
            const float w11 = wx1 * wy1;
            fptr[2 * e]     = fmaf(w00, t00.x, fmaf(w10, t10.x, fmaf(w01, t01.x, w11 * t11.x)));
            fptr[2 * e + 1] = fmaf(w00, t00.y, fmaf(w10, t10.y, fmaf(w01, t01.y, w11 * t11.y)));
        }
    }
    __syncthreads();

    // ---- Phase 1: h1[j], j = 16q + jj --------------------------------------
    {
        float acc1[16];
        #pragma unroll
        for (int jj = 0; jj < 16; ++jj) acc1[jj] = b1[q * 16 + jj];

        const float* fbase = fo_s + lane * FSTRIDE;
        #pragma unroll
        for (int fc = 0; fc < 2; ++fc) {
            float fv[16];
            #pragma unroll
            for (int t = 0; t < 16; ++t) fv[t] = fbase[fc * 16 + t];
            #pragma unroll
            for (int jj = 0; jj < 16; ++jj) {
                const float* __restrict__ w1r = W1 + (q * 16 + jj) * 32 + fc * 16;
                #pragma unroll
                for (int t = 0; t < 16; ++t) acc1[jj] = fmaf(w1r[t], fv[t], acc1[jj]);
            }
        }
        float* hptr = h1_s + lane * HSTRIDE + q * 16;
        #pragma unroll
        for (int jj = 0; jj < 16; ++jj) hptr[jj] = fmaxf(acc1[jj], 0.0f);
    }
    __syncthreads();   // h1 ready; also: all feat reads done -> fo_s reusable

    // ---- Phase 2: h2[j] + layer-3 partials ---------------------------------
    {
        float acc2[16];
        #pragma unroll
        for (int jj = 0; jj < 16; ++jj) acc2[jj] = b2[q * 16 + jj];

        const float* hbase = h1_s + lane * HSTRIDE;
        #pragma unroll
        for (int kc = 0; kc < 4; ++kc) {
            float hv[16];
            #pragma unroll
            for (int t = 0; t < 16; ++t) hv[t] = hbase[kc * 16 + t];
            #pragma unroll
            for (int jj = 0; jj < 16; ++jj) {
                const float* __restrict__ w2r = W2 + (q * 16 + jj) * 64 + kc * 16;
                #pragma unroll
                for (int t = 0; t < 16; ++t) acc2[jj] = fmaf(w2r[t], hv[t], acc2[jj]);
            }
        }
        float o0 = 0.0f, o1 = 0.0f, o2 = 0.0f;
        #pragma unroll
        for (int jj = 0; jj < 16; ++jj) {
            const int j = q * 16 + jj;
            const float h2j = fmaxf(acc2[jj], 0.0f);
            o0 = fmaf(W3[j],       h2j, o0);
            o1 = fmaf(W3[64 + j],  h2j, o1);
            o2 = fmaf(W3[128 + j], h2j, o2);
        }
        float* optr = fo_s + lane * OSTRIDE + q * 3;   // fo_s reused as o_part
        optr[0] = o0; optr[1] = o1; optr[2] = o2;
    }
    __syncthreads();

    // ---- Final: wave 0 reduces quarters and stores -------------------------
    if (tid < 64 && live) {
        const float* op = fo_s + tid * OSTRIDE;
        const float r0 = b3[0] + ((op[0] + op[3]) + (op[6] + op[9]));
        const float r1 = b3[1] + ((op[1] + op[4]) + (op[7] + op[10]));
        const float r2 = b3[2] + ((op[2] + op[5]) + (op[8] + op[11]));
        float* optr = out + 3 * s;
        optr[0] = r0; optr[1] = r1; optr[2] = r2;
    }
}

extern "C" void kernel_launch(void* const* d_in, const int* in_sizes, int n_in,
                              void* d_out, int out_size, void* d_ws, size_t ws_size,
                              hipStream_t stream) {
    const float* x      = (const float*)d_in[0];
    const float* tables = (const float*)d_in[1];
    const float* W1     = (const float*)d_in[2];
    const float* b1v    = (const float*)d_in[3];
    const float* W2     = (const float*)d_in[4];
    const float* b2v    = (const float*)d_in[5];
    const float* W3     = (const float*)d_in[6];
    const float* b3v    = (const float*)d_in[7];
    float* out = (float*)d_out;

    const int n = in_sizes[0] / 2;   // B

    // Replicate numpy's RES computation on the host (glibc libm, float64).
    ResArr ra;
    const double bb = exp((log(512.0) - log(16.0)) / 15.0);
    for (int k = 0; k < 16; ++k) ra.r[k] = (float)floor(16.0 * pow(bb, (double)k));

    dim3 grid((n + 63) / 64), block(256);
    hipLaunchKernelGGL(mh_fused, grid, block, 0, stream,
                       x, tables, W1, b1v, W2, b2v, W3, b3v, out, ra, n);
}

// Round 5
// 561.454 us; speedup vs baseline: 1.5310x; 1.5310x over previous
//
#include <hip/hip_runtime.h>
#include <math.h>

// MultiHash: Instant-NGP style 2D multires hash encoding (L=16, T=2^14, F=2)
// + MLP 32 -> 64 -> 64 -> 3, fp32 throughout (threshold 8.9e-8 abs forbids bf16).
//
// R5: thread-per-sample (R1 structure, NO barriers — R4 showed barrier-aligned
// stalls collapse VALUBusy to 25%), with the 64-live-float cut broken via a
// 32-float per-thread PRIVATE LDS slot:
//   - feat[32] -> LDS (addr = tid*4 + k*1024: bank = lane%32, 2-way = free,
//     all offsets compile-time immediates; private -> no syncthreads ever).
//   - h1 in two 32-reg halves; h1a idles (cheap one-time AGPR stash) while
//     h1b accumulates; relu(h1a) then overwrites dead feat slots in LDS.
//   - layer2 in two 32-accumulator halves; k-chunks staged 16-at-a-time from
//     LDS (h1a) / regs (h1b). Hot live set stays ~56 VGPRs -> no hot-loop
//     spills (R1-R3: 64-float arrays got AGPR'd at ~12k extra VALU/wave).
//   - weights via wave-uniform s_load_dwordx16 (row-major 16-chunks); j-loops
//     unroll 4 -> 4 independent SMEM chains in flight.
// LDS 32KB/block -> 5 blocks/CU -> 62% occupancy ceiling.
// Issue floor: ~7.2k VALU/thread -> ~96 us; predict 120-160 us.

#define TBL_MASK 16383u
#define PRIME1   2654435761u

struct ResArr { float r[16]; };

__global__ __launch_bounds__(256) void mh_fused(
    const float* __restrict__ x,
    const float* __restrict__ tables,
    const float* __restrict__ W1,
    const float* __restrict__ b1,
    const float* __restrict__ W2,
    const float* __restrict__ b2,
    const float* __restrict__ W3,
    const float* __restrict__ b3,
    float* __restrict__ out,
    ResArr res, int n)
{
    __shared__ float sc[32 * 256];      // 32 KB: 32 private floats per thread
    const int tid = threadIdx.x;
    const long s  = (long)blockIdx.x * 256 + tid;
    if (s >= (long)n) return;

    float* sl = sc + tid;               // element k lives at sl[k*256]

    const float2 xv = reinterpret_cast<const float2*>(x)[s];
    const float2* __restrict__ tbl2 = reinterpret_cast<const float2*>(tables);

    // ---- Phase E: encoding -> feat into LDS slots 0..31 --------------------
    #pragma unroll 4
    for (int l = 0; l < 16; ++l) {
        const float r  = res.r[l];
        const float sx = xv.x * r;
        const float sy = xv.y * r;
        const float gx = floorf(sx);
        const float gy = floorf(sy);
        const unsigned ux = (unsigned)(int)gx;
        const unsigned uy = (unsigned)(int)gy;
        const unsigned hy0 = uy * PRIME1;
        const unsigned hy1 = hy0 + PRIME1;          // (uy+1)*PRIME1 mod 2^32
        const unsigned i00 = ( ux       ^ hy0) & TBL_MASK;
        const unsigned i10 = ((ux + 1u) ^ hy0) & TBL_MASK;
        const unsigned i01 = ( ux       ^ hy1) & TBL_MASK;
        const unsigned i11 = ((ux + 1u) ^ hy1) & TBL_MASK;
        const float2* tl = tbl2 + (l << 14);
        const float2 t00 = tl[i00];
        const float2 t10 = tl[i10];
        const float2 t01 = tl[i01];
        const float2 t11 = tl[i11];
        const float wx0 = 1.0f - fabsf(sx - gx);
        const float wx1 = 1.0f - fabsf(sx - (gx + 1.0f));
        const float wy0 = 1.0f - fabsf(sy - gy);
        const float wy1 = 1.0f - fabsf(sy - (gy + 1.0f));
        const float w00 = wx0 * wy0;
        const float w10 = wx1 * wy0;
        const float w01 = wx0 * wy1;
        const float w11 = wx1 * wy1;
        sl[(2 * l) * 256] =
            fmaf(w00, t00.x, fmaf(w10, t10.x, fmaf(w01, t01.x, w11 * t11.x)));
        sl[(2 * l + 1) * 256] =
            fmaf(w00, t00.y, fmaf(w10, t10.y, fmaf(w01, t01.y, w11 * t11.y)));
    }

    // ---- Layer 1: h1a = rows 0..31 (regs), h1b = rows 32..63 (regs) --------
    float h1a[32];
    #pragma unroll
    for (int j = 0; j < 32; ++j) h1a[j] = b1[j];
    #pragma unroll
    for (int fh = 0; fh < 2; ++fh) {
        float fv[16];
        #pragma unroll
        for (int t = 0; t < 16; ++t) fv[t] = sl[(fh * 16 + t) * 256];
        #pragma unroll 4
        for (int j = 0; j < 32; ++j) {
            const float* __restrict__ w1r = W1 + j * 32 + fh * 16;
            #pragma unroll
            for (int t = 0; t < 16; ++t) h1a[j] = fmaf(w1r[t], fv[t], h1a[j]);
        }
    }

    float h1b[32];
    #pragma unroll
    for (int j = 0; j < 32; ++j) h1b[j] = b1[32 + j];
    #pragma unroll
    for (int fh = 0; fh < 2; ++fh) {
        float fv[16];
        #pragma unroll
        for (int t = 0; t < 16; ++t) fv[t] = sl[(fh * 16 + t) * 256];
        #pragma unroll 4
        for (int j = 0; j < 32; ++j) {
            const float* __restrict__ w1r = W1 + (32 + j) * 32 + fh * 16;
            #pragma unroll
            for (int t = 0; t < 16; ++t) h1b[j] = fmaf(w1r[t], fv[t], h1b[j]);
        }
    }

    // feat dead now: overwrite LDS slots with relu(h1a); relu h1b in regs
    #pragma unroll
    for (int j = 0; j < 32; ++j) sl[j * 256] = fmaxf(h1a[j], 0.0f);
    #pragma unroll
    for (int j = 0; j < 32; ++j) h1b[j] = fmaxf(h1b[j], 0.0f);

    // ---- Layer 2 + fused layer 3 -------------------------------------------
    float o0 = b3[0], o1 = b3[1], o2 = b3[2];
    #pragma unroll
    for (int half = 0; half < 2; ++half) {
        float acc[32];
        #pragma unroll
        for (int j = 0; j < 32; ++j) acc[j] = b2[half * 32 + j];
        #pragma unroll
        for (int kq = 0; kq < 4; ++kq) {
            float hv[16];
            if (kq < 2) {
                #pragma unroll
                for (int t = 0; t < 16; ++t) hv[t] = sl[(kq * 16 + t) * 256];
            } else {
                #pragma unroll
                for (int t = 0; t < 16; ++t) hv[t] = h1b[(kq - 2) * 16 + t];
            }
            #pragma unroll 4
            for (int j = 0; j < 32; ++j) {
                const float* __restrict__ w2r = W2 + (half * 32 + j) * 64 + kq * 16;
                #pragma unroll
                for (int t = 0; t < 16; ++t) acc[j] = fmaf(w2r[t], hv[t], acc[j]);
            }
        }
        #pragma unroll
        for (int j = 0; j < 32; ++j) {
            const int jg = half * 32 + j;
            const float h2j = fmaxf(acc[j], 0.0f);
            o0 = fmaf(W3[jg],       h2j, o0);
            o1 = fmaf(W3[64 + jg],  h2j, o1);
            o2 = fmaf(W3[128 + jg], h2j, o2);
        }
    }

    float* op = out + 3 * s;
    op[0] = o0; op[1] = o1; op[2] = o2;
}

extern "C" void kernel_launch(void* const* d_in, const int* in_sizes, int n_in,
                              void* d_out, int out_size, void* d_ws, size_t ws_size,
                              hipStream_t stream) {
    const float* x      = (const float*)d_in[0];
    const float* tables = (const float*)d_in[1];
    const float* W1     = (const float*)d_in[2];
    const float* b1v    = (const float*)d_in[3];
    const float* W2     = (const float*)d_in[4];
    const float* b2v    = (const float*)d_in[5];
    const float* W3     = (const float*)d_in[6];
    const float* b3v    = (const float*)d_in[7];
    float* out = (float*)d_out;

    const int n = in_sizes[0] / 2;   // B

    // Replicate numpy's RES computation on the host (glibc libm, float64).
    ResArr ra;
    const double bb = exp((log(512.0) - log(16.0)) / 15.0);
    for (int k = 0; k < 16; ++k) ra.r[k] = (float)floor(16.0 * pow(bb, (double)k));

    dim3 grid((n + 255) / 256), block(256);
    hipLaunchKernelGGL(mh_fused, grid, block, 0, stream,
                       x, tables, W1, b1v, W2, b2v, W3, b3v, out, ra, n);
}

// Round 6
// 238.631 us; speedup vs baseline: 3.6023x; 2.3528x over previous
//
#include <hip/hip_runtime.h>
#include <hip/hip_bf16.h>
#include <math.h>

// MultiHash: Instant-NGP 2D multires hash encoding (L=16, T=2^14, F=2)
// + MLP 32 -> 64 -> 64 -> 3 over B=1M samples.
//
// R6: move the MLP (6.3k of 6.8k MACs/sample) from the saturated fp32 VALU
// pipe (R1-R5: 250-390us of VALU time, AGPR-stash tax on any >48-float live
// set) onto the idle MFMA pipe, in SPLIT-bf16 (x = hi + lo bf16;
// A*B = Ahi*Bhi + Ahi*Blo + Alo*Bhi, lo*lo dropped ~2^-18) so quantization
// error (~2^-17 rel) is far below the 8.9e-8 abs threshold.
//
// Structure (per wave = 64 samples; block = 64 threads = 1 wave -> NO
// __syncthreads anywhere, the R4 lesson):
//  - encoding: lane = sample, same exact math as R1 (known-good).
//  - feat staged in LDS row-major [sample][k] as separate hi/lo bf16 arrays,
//    row stride 40 ushort (80 B: 16B-aligned for b128, bank-shift 20%32
//    -> conflict-light). A-frag (A[m=lane&15][k=quad*8+j], m120-verified
//    layout) = ONE ds_read_b128 per fragment.
//  - B-frags = weights, split in-register from global loads (rows are
//    lane-uniform-ish, all L1/L2-resident; reconverted per wave - cheap).
//  - C/D layout col=lane&15, row=quad*4+reg (m89/m91-verified). Samples = M.
//  - M=64 split into two 32-sample halves to cap live accumulators at 32
//    VGPRs per layer phase; h1/h2 share ONE LDS region (同-wave DS ops are
//    in-order -> overwrite after A-frag reads is safe). LDS = 19456 B
//    -> 8 waves/CU.
//  - layer3: B = W3 rows (lanes ln<3, zeros otherwise), C cols 0..2 stored.

#define TBL_MASK 16383u
#define PRIME1   2654435761u

typedef __attribute__((ext_vector_type(8))) short short8;
typedef __attribute__((ext_vector_type(4))) float f32x4;
typedef __attribute__((ext_vector_type(4))) unsigned int uint4v;

struct ResArr { float r[16]; };

__device__ __forceinline__ unsigned short bf16rn(float f) {
    __hip_bfloat16 h = __float2bfloat16(f);   // RNE
    return __builtin_bit_cast(unsigned short, h);
}
__device__ __forceinline__ float bf16tof(unsigned short u) {
    unsigned int x = ((unsigned int)u) << 16;
    return __builtin_bit_cast(float, x);
}

// Split 8 contiguous fp32 (16B-aligned) into hi/lo bf16 fragments.
__device__ __forceinline__ void splitW(const float* __restrict__ p,
                                       short8& hi, short8& lo) {
    const float4 w0 = *(const float4*)p;
    const float4 w1 = *(const float4*)(p + 4);
    float v[8] = {w0.x, w0.y, w0.z, w0.w, w1.x, w1.y, w1.z, w1.w};
    #pragma unroll
    for (int e = 0; e < 8; ++e) {
        const unsigned short hb = bf16rn(v[e]);
        const unsigned short lb = bf16rn(v[e] - bf16tof(hb));
        hi[e] = (short)hb;
        lo[e] = (short)lb;
    }
}

__device__ __forceinline__ void splitWm(const float* __restrict__ p, bool valid,
                                        short8& hi, short8& lo) {
    float v[8];
    if (valid) {
        const float4 w0 = *(const float4*)p;
        const float4 w1 = *(const float4*)(p + 4);
        v[0] = w0.x; v[1] = w0.y; v[2] = w0.z; v[3] = w0.w;
        v[4] = w1.x; v[5] = w1.y; v[6] = w1.z; v[7] = w1.w;
    } else {
        #pragma unroll
        for (int e = 0; e < 8; ++e) v[e] = 0.0f;
    }
    #pragma unroll
    for (int e = 0; e < 8; ++e) {
        const unsigned short hb = bf16rn(v[e]);
        const unsigned short lb = bf16rn(v[e] - bf16tof(hb));
        hi[e] = (short)hb;
        lo[e] = (short)lb;
    }
}

__device__ __forceinline__ short8 ldsFrag(const unsigned short* p) {
    return __builtin_bit_cast(short8, *(const uint4v*)p);
}

#define MFMA(a, b, c) __builtin_amdgcn_mfma_f32_16x16x32_bf16((a), (b), (c), 0, 0, 0)

__global__ __launch_bounds__(64) void mh_mfma(
    const float* __restrict__ x,
    const float* __restrict__ tables,
    const float* __restrict__ W1,
    const float* __restrict__ b1,
    const float* __restrict__ W2,
    const float* __restrict__ b2,
    const float* __restrict__ W3,
    const float* __restrict__ b3,
    float* __restrict__ out,
    ResArr res, int n)
{
    // feat: [64 samples][32 k] bf16, row stride 40 ushort (80 B)
    __shared__ unsigned short sFH[64 * 40];
    __shared__ unsigned short sFL[64 * 40];
    // h1/h2 shared region: [32 rows][64 cols] bf16, row stride 72 ushort (144 B)
    __shared__ unsigned short sAH[32 * 72];
    __shared__ unsigned short sAL[32 * 72];

    const int L  = threadIdx.x;
    const int ln = L & 15;
    const int q  = L >> 4;
    const long base = (long)blockIdx.x * 64;
    long s = base + L;
    if (s >= (long)n) s = (long)n - 1;   // clamp loads; stores predicated below

    const float2 xv = reinterpret_cast<const float2*>(x)[s];
    const float2* __restrict__ tbl2 = reinterpret_cast<const float2*>(tables);

    // ---- encoding: exact same math as R1 (validated); split+pack into LDS --
    #pragma unroll 4
    for (int l = 0; l < 16; ++l) {
        const float r  = res.r[l];
        const float sx = xv.x * r;
        const float sy = xv.y * r;
        const float gx = floorf(sx);
        const float gy = floorf(sy);
        const unsigned ux = (unsigned)(int)gx;
        const unsigned uy = (unsigned)(int)gy;
        const unsigned hy0 = uy * PRIME1;
        const unsigned hy1 = hy0 + PRIME1;
        const unsigned i00 = ( ux       ^ hy0) & TBL_MASK;
        const unsigned i10 = ((ux + 1u) ^ hy0) & TBL_MASK;
        const unsigned i01 = ( ux       ^ hy1) & TBL_MASK;
        const unsigned i11 = ((ux + 1u) ^ hy1) & TBL_MASK;
        const float2* tl = tbl2 + (l << 14);
        const float2 t00 = tl[i00];
        const float2 t10 = tl[i10];
        const float2 t01 = tl[i01];
        const float2 t11 = tl[i11];
        const float wx0 = 1.0f - fabsf(sx - gx);
        const float wx1 = 1.0f - fabsf(sx - (gx + 1.0f));
        const float wy0 = 1.0f - fabsf(sy - gy);
        const float wy1 = 1.0f - fabsf(sy - (gy + 1.0f));
        const float w00 = wx0 * wy0;
        const float w10 = wx1 * wy0;
        const float w01 = wx0 * wy1;
        const float w11 = wx1 * wy1;
        const float f0 = fmaf(w00, t00.x, fmaf(w10, t10.x, fmaf(w01, t01.x, w11 * t11.x)));
        const float f1 = fmaf(w00, t00.y, fmaf(w10, t10.y, fmaf(w01, t01.y, w11 * t11.y)));
        const unsigned short h0 = bf16rn(f0);
        const unsigned short h1e = bf16rn(f1);
        const unsigned short l0 = bf16rn(f0 - bf16tof(h0));
        const unsigned short l1 = bf16rn(f1 - bf16tof(h1e));
        *(unsigned int*)&sFH[L * 40 + 2 * l] = (unsigned)h0 | ((unsigned)h1e << 16);
        *(unsigned int*)&sFL[L * 40 + 2 * l] = (unsigned)l0 | ((unsigned)l1 << 16);
    }

    // biases (per-lane by output column)
    float b1v[4], b2v[4];
    #pragma unroll
    for (int nt = 0; nt < 4; ++nt) { b1v[nt] = b1[nt * 16 + ln]; b2v[nt] = b2[nt * 16 + ln]; }
    const float b3v = (ln < 3) ? b3[ln] : 0.0f;

    const f32x4 zero4 = {0.0f, 0.0f, 0.0f, 0.0f};

    for (int mh = 0; mh < 2; ++mh) {          // 32-sample halves
        // ---------------- layer 1 ----------------
        short8 a1h[2], a1l[2];
        #pragma unroll
        for (int mt = 0; mt < 2; ++mt) {
            const int row = mh * 32 + mt * 16 + ln;
            a1h[mt] = ldsFrag(&sFH[row * 40 + q * 8]);
            a1l[mt] = ldsFrag(&sFL[row * 40 + q * 8]);
        }
        f32x4 acc1[2][4];
        #pragma unroll
        for (int mt = 0; mt < 2; ++mt)
            #pragma unroll
            for (int nt = 0; nt < 4; ++nt) acc1[mt][nt] = zero4;

        #pragma unroll
        for (int nt = 0; nt < 4; ++nt) {
            short8 bh, bl;
            splitW(W1 + (nt * 16 + ln) * 32 + q * 8, bh, bl);
            #pragma unroll
            for (int mt = 0; mt < 2; ++mt) {
                f32x4 a = acc1[mt][nt];
                a = MFMA(a1l[mt], bh, a);
                a = MFMA(a1h[mt], bl, a);
                a = MFMA(a1h[mt], bh, a);
                acc1[mt][nt] = a;
            }
        }
        // epilogue: bias + relu + split -> sAH/sAL rows 0..31
        #pragma unroll
        for (int mt = 0; mt < 2; ++mt)
            #pragma unroll
            for (int nt = 0; nt < 4; ++nt) {
                const int col = nt * 16 + ln;
                #pragma unroll
                for (int r = 0; r < 4; ++r) {
                    float v = fmaxf(acc1[mt][nt][r] + b1v[nt], 0.0f);
                    const unsigned short hb = bf16rn(v);
                    const unsigned short lb = bf16rn(v - bf16tof(hb));
                    const int rl = mt * 16 + q * 4 + r;
                    sAH[rl * 72 + col] = hb;
                    sAL[rl * 72 + col] = lb;
                }
            }

        // ---------------- layer 2 ----------------
        short8 a2h[2][2], a2l[2][2];
        #pragma unroll
        for (int mt = 0; mt < 2; ++mt)
            #pragma unroll
            for (int ks = 0; ks < 2; ++ks) {
                const int row = mt * 16 + ln;
                a2h[mt][ks] = ldsFrag(&sAH[row * 72 + ks * 32 + q * 8]);
                a2l[mt][ks] = ldsFrag(&sAL[row * 72 + ks * 32 + q * 8]);
            }
        f32x4 acc2[2][4];
        #pragma unroll
        for (int mt = 0; mt < 2; ++mt)
            #pragma unroll
            for (int nt = 0; nt < 4; ++nt) acc2[mt][nt] = zero4;

        #pragma unroll
        for (int nt = 0; nt < 4; ++nt)
            #pragma unroll
            for (int ks = 0; ks < 2; ++ks) {
                short8 bh, bl;
                splitW(W2 + (nt * 16 + ln) * 64 + ks * 32 + q * 8, bh, bl);
                #pragma unroll
                for (int mt = 0; mt < 2; ++mt) {
                    f32x4 a = acc2[mt][nt];
                    a = MFMA(a2l[mt][ks], bh, a);
                    a = MFMA(a2h[mt][ks], bl, a);
                    a = MFMA(a2h[mt][ks], bh, a);
                    acc2[mt][nt] = a;
                }
            }
        // epilogue: bias + relu + split -> overwrite sAH/sAL (same-wave DS
        // ops are processed in order; A-frags above were already read)
        #pragma unroll
        for (int mt = 0; mt < 2; ++mt)
            #pragma unroll
            for (int nt = 0; nt < 4; ++nt) {
                const int col = nt * 16 + ln;
                #pragma unroll
                for (int r = 0; r < 4; ++r) {
                    float v = fmaxf(acc2[mt][nt][r] + b2v[nt], 0.0f);
                    const unsigned short hb = bf16rn(v);
                    const unsigned short lb = bf16rn(v - bf16tof(hb));
                    const int rl = mt * 16 + q * 4 + r;
                    sAH[rl * 72 + col] = hb;
                    sAL[rl * 72 + col] = lb;
                }
            }

        // ---------------- layer 3 ----------------
        short8 a3h[2][2], a3l[2][2];
        #pragma unroll
        for (int mt = 0; mt < 2; ++mt)
            #pragma unroll
            for (int ks = 0; ks < 2; ++ks) {
                const int row = mt * 16 + ln;
                a3h[mt][ks] = ldsFrag(&sAH[row * 72 + ks * 32 + q * 8]);
                a3l[mt][ks] = ldsFrag(&sAL[row * 72 + ks * 32 + q * 8]);
            }
        f32x4 acc3[2] = {zero4, zero4};
        #pragma unroll
        for (int ks = 0; ks < 2; ++ks) {
            short8 bh, bl;
            splitWm(W3 + ln * 64 + ks * 32 + q * 8, ln < 3, bh, bl);
            #pragma unroll
            for (int mt = 0; mt < 2; ++mt) {
                f32x4 a = acc3[mt];
                a = MFMA(a3l[mt][ks], bh, a);
                a = MFMA(a3h[mt][ks], bl, a);
                a = MFMA(a3h[mt][ks], bh, a);
                acc3[mt] = a;
            }
        }
        // store: C col = ln (channel, <3), rows = samples
        if (ln < 3) {
            #pragma unroll
            for (int mt = 0; mt < 2; ++mt)
                #pragma unroll
                for (int r = 0; r < 4; ++r) {
                    const long sg = base + mh * 32 + mt * 16 + q * 4 + r;
                    if (sg < (long)n) out[sg * 3 + ln] = acc3[mt][r] + b3v;
                }
        }
    }
}

extern "C" void kernel_launch(void* const* d_in, const int* in_sizes, int n_in,
                              void* d_out, int out_size, void* d_ws, size_t ws_size,
                              hipStream_t stream) {
    const float* x      = (const float*)d_in[0];
    const float* tables = (const float*)d_in[1];
    const float* W1     = (const float*)d_in[2];
    const float* b1v    = (const float*)d_in[3];
    const float* W2     = (const float*)d_in[4];
    const float* b2v    = (const float*)d_in[5];
    const float* W3     = (const float*)d_in[6];
    const float* b3v    = (const float*)d_in[7];
    float* out = (float*)d_out;

    const int n = in_sizes[0] / 2;   // B

    // Replicate numpy's RES computation on the host (glibc libm, float64).
    ResArr ra;
    const double bb = exp((log(512.0) - log(16.0)) / 15.0);
    for (int k = 0; k < 16; ++k) ra.r[k] = (float)floor(16.0 * pow(bb, (double)k));

    dim3 grid((n + 63) / 64), block(64);
    hipLaunchKernelGGL(mh_mfma, grid, block, 0, stream,
                       x, tables, W1, b1v, W2, b2v, W3, b3v, out, ra, n);
}